// Round 1
// baseline (162.305 us; speedup 1.0000x reference)
//
#include <hip/hip_runtime.h>
#include <hip/hip_bf16.h>

#define B_ 4
#define N_ 2048
#define M_ 2048
#define C_ 256
#define H_ 8
#define DH_ 32
#define R_ 128

typedef __bf16 bf16x8 __attribute__((ext_vector_type(8)));
typedef float f32x4 __attribute__((ext_vector_type(4)));

// ---------------- Kernel 0: W^T (f32 -> bf16) for Wq, Wk, Wv ----------------
__global__ __launch_bounds__(256) void wtrans_kernel(
    const float* __restrict__ Wq, const float* __restrict__ Wk,
    const float* __restrict__ Wv, __bf16* __restrict__ out)
{
    __shared__ float t[32][33];
    int pz = blockIdx.z;
    const float* W = pz == 0 ? Wq : (pz == 1 ? Wk : Wv);
    int j0 = blockIdx.x * 32, k0 = blockIdx.y * 32;
    int tx = threadIdx.x, ty = threadIdx.y;
#pragma unroll
    for (int i = 0; i < 4; ++i)
        t[ty + 8 * i][tx] = W[(k0 + ty + 8 * i) * C_ + j0 + tx];
    __syncthreads();
    __bf16* o = out + (size_t)pz * C_ * C_;
#pragma unroll
    for (int i = 0; i < 4; ++i)
        o[(j0 + ty + 8 * i) * C_ + k0 + tx] = (__bf16)t[tx][ty + 8 * i];
}

// ---------------- Kernel 1: projections X@W+b -> bf16, head layouts ----------
// pz=0: q -> (B,H,N,Dh); pz=1: k -> (B,H,M,Dh); pz=2: v -> (B,H,Dh,M) transposed
__global__ __launch_bounds__(256) void proj_kernel(
    const float* __restrict__ Xq, const float* __restrict__ Xk, const float* __restrict__ Xv,
    const float* __restrict__ bq, const float* __restrict__ bk, const float* __restrict__ bv,
    const __bf16* __restrict__ Wt,
    __bf16* __restrict__ qb, __bf16* __restrict__ kb, __bf16* __restrict__ vt)
{
    int pz = blockIdx.z;
    const float* X = pz == 0 ? Xq : (pz == 1 ? Xk : Xv);
    const float* bias = pz == 0 ? bq : (pz == 1 ? bk : bv);
    const __bf16* W = Wt + (size_t)pz * C_ * C_;

    int r0 = blockIdx.x * 64, c0 = blockIdx.y * 64;
    int w = threadIdx.x >> 6, lane = threadIdx.x & 63;
    int lg = lane >> 4, lr = lane & 15;
    int rw = r0 + w * 16;

    f32x4 z = {0.f, 0.f, 0.f, 0.f};
    f32x4 acc[4] = {z, z, z, z};

    for (int ks = 0; ks < 8; ++ks) {
        const float* ap = X + (size_t)(rw + lr) * C_ + ks * 32 + lg * 8;
        float4 a0 = *(const float4*)ap;
        float4 a1 = *(const float4*)(ap + 4);
        bf16x8 af;
        af[0] = (__bf16)a0.x; af[1] = (__bf16)a0.y; af[2] = (__bf16)a0.z; af[3] = (__bf16)a0.w;
        af[4] = (__bf16)a1.x; af[5] = (__bf16)a1.y; af[6] = (__bf16)a1.z; af[7] = (__bf16)a1.w;
#pragma unroll
        for (int ns = 0; ns < 4; ++ns) {
            bf16x8 bfv = *(const bf16x8*)(W + (size_t)(c0 + ns * 16 + lr) * C_ + ks * 32 + lg * 8);
            acc[ns] = __builtin_amdgcn_mfma_f32_16x16x32_bf16(af, bfv, acc[ns], 0, 0, 0);
        }
    }

#pragma unroll
    for (int ns = 0; ns < 4; ++ns) {
        int j = c0 + ns * 16 + lr;
        float bj = bias[j];
        int h = j >> 5, d = j & 31;
#pragma unroll
        for (int reg = 0; reg < 4; ++reg) {
            int r = rw + lg * 4 + reg;
            int bb = r >> 11, n = r & (N_ - 1);
            float val = acc[ns][reg] + bj;
            if (pz == 0)
                qb[(((size_t)bb * H_ + h) * N_ + n) * DH_ + d] = (__bf16)val;
            else if (pz == 1)
                kb[(((size_t)bb * H_ + h) * M_ + n) * DH_ + d] = (__bf16)val;
            else
                vt[(((size_t)bb * H_ + h) * DH_ + d) * M_ + n] = (__bf16)val;
        }
    }
}

// ---------------- Kernel 2: fused LRPE flash attention ----------------------
// grid (N/16, B), block 512 (8 waves = 8 heads). Q-tile = 16 rows.
__global__ __launch_bounds__(512) void attn_kernel(
    const __bf16* __restrict__ qb, const __bf16* __restrict__ kb,
    const __bf16* __restrict__ vt, const int* __restrict__ ridx,
    const float* __restrict__ kmask, const float* __restrict__ rbank,
    float* __restrict__ out)
{
    __shared__ int idxS[16][66];           // padded: <=2-way conflicts on gather
    __shared__ __bf16 Pall[H_][16][R_];    // per-head q.rpe scores (bf16)
    __shared__ __bf16 Pt[H_][1024];        // per-wave P transpose buffer (XOR-swizzled)

    int b = blockIdx.y;
    int n0 = blockIdx.x * 16;
    int h = threadIdx.x >> 6, lane = threadIdx.x & 63;
    int lg = lane >> 4, lr = lane & 15;

    f32x4 z = {0.f, 0.f, 0.f, 0.f};

    // Q fragment (16 rows x K=32), rows = lr, k = 8*lg..+8
    bf16x8 qf = *(const bf16x8*)(qb + (((size_t)b * H_ + h) * N_ + n0 + lr) * DH_ + lg * 8);

    // P_all = Q @ rpe_h^T  (16 x 128), 8 MFMAs
    for (int rs = 0; rs < R_ / 16; ++rs) {
        const float* rp = rbank + (size_t)(rs * 16 + lr) * C_ + h * DH_ + lg * 8;
        float4 r0v = *(const float4*)rp;
        float4 r1v = *(const float4*)(rp + 4);
        bf16x8 rf;
        rf[0] = (__bf16)r0v.x; rf[1] = (__bf16)r0v.y; rf[2] = (__bf16)r0v.z; rf[3] = (__bf16)r0v.w;
        rf[4] = (__bf16)r1v.x; rf[5] = (__bf16)r1v.y; rf[6] = (__bf16)r1v.z; rf[7] = (__bf16)r1v.w;
        f32x4 pc = __builtin_amdgcn_mfma_f32_16x16x32_bf16(qf, rf, z, 0, 0, 0);
#pragma unroll
        for (int reg = 0; reg < 4; ++reg)
            Pall[h][lg * 4 + reg][rs * 16 + lr] = (__bf16)pc[reg];
    }

    const float scale = 0.17677669529663687f; // 1/sqrt(32)
    float mrun[4], lrun[4];
    f32x4 acc[2] = {z, z};
#pragma unroll
    for (int r = 0; r < 4; ++r) { mrun[r] = -1e30f; lrun[r] = 0.f; }

    const __bf16* Kh = kb + ((size_t)b * H_ + h) * M_ * DH_;
    const __bf16* Vh = vt + ((size_t)b * H_ + h) * DH_ * M_;
    const float* km = kmask + (size_t)b * M_;
    const int* ixb = ridx + ((size_t)b * N_ + n0) * M_;
    char* ptb = (char*)&Pt[h][0];

    for (int mt = 0; mt < M_ / 64; ++mt) {
        int m0 = mt * 64;
        __syncthreads();
        {
            int t = threadIdx.x;
            int row = t >> 5, c = (t & 31) * 2;
            int2 iv = *(const int2*)(ixb + (size_t)row * M_ + m0 + c);
            idxS[row][c] = iv.x; idxS[row][c + 1] = iv.y;
        }
        __syncthreads();

        // S = Q @ K^T for 4 m-subtiles of 16
        f32x4 s[4];
#pragma unroll
        for (int ms = 0; ms < 4; ++ms) {
            bf16x8 kf = *(const bf16x8*)(Kh + (size_t)(m0 + ms * 16 + lr) * DH_ + lg * 8);
            s[ms] = __builtin_amdgcn_mfma_f32_16x16x32_bf16(qf, kf, z, 0, 0, 0);
        }

        // add gathered RPE score + mask, scale
        float sv[4][4];
#pragma unroll
        for (int ms = 0; ms < 4; ++ms) {
            int ml = ms * 16 + lr;
            float mk = km[m0 + ml];
#pragma unroll
            for (int reg = 0; reg < 4; ++reg) {
                int n = lg * 4 + reg;
                int i = idxS[n][ml];
                float p = (float)Pall[h][n][i];
                sv[ms][reg] = (s[ms][reg] + p) * scale + mk;
            }
        }

        // online softmax (row = (lg*4+reg); reduce across 16 lanes of the group)
        float pq[4][4];
#pragma unroll
        for (int reg = 0; reg < 4; ++reg) {
            float mx = fmaxf(fmaxf(sv[0][reg], sv[1][reg]), fmaxf(sv[2][reg], sv[3][reg]));
#pragma unroll
            for (int off = 1; off < 16; off <<= 1)
                mx = fmaxf(mx, __shfl_xor(mx, off, 16));
            float mnew = fmaxf(mrun[reg], mx);
            float alpha = __expf(mrun[reg] - mnew);
            float sum = 0.f;
#pragma unroll
            for (int ms = 0; ms < 4; ++ms) {
                float p = __expf(sv[ms][reg] - mnew);
                pq[ms][reg] = p; sum += p;
            }
#pragma unroll
            for (int off = 1; off < 16; off <<= 1)
                sum += __shfl_xor(sum, off, 16);
            lrun[reg] = lrun[reg] * alpha + sum;
            mrun[reg] = mnew;
            acc[0][reg] *= alpha;
            acc[1][reg] *= alpha;
        }

        // P -> LDS (bf16, XOR-swizzled rows to avoid 128B-stride bank conflicts)
#pragma unroll
        for (int ms = 0; ms < 4; ++ms) {
#pragma unroll
            for (int reg = 0; reg < 4; ++reg) {
                int n = lg * 4 + reg;
                int byteoff = ((n * 64 + ms * 16 + lr) * 2) ^ ((n & 7) << 4);
                *(__bf16*)(ptb + byteoff) = (__bf16)pq[ms][reg];
            }
        }

        // out += P @ V  (A-frags from swizzled Pt, B-frags from transposed V)
#pragma unroll
        for (int ks = 0; ks < 2; ++ks) {
            int byteoff = ((lr * 64 + ks * 32 + lg * 8) * 2) ^ ((lr & 7) << 4);
            bf16x8 pf = *(const bf16x8*)(ptb + byteoff);
#pragma unroll
            for (int ds = 0; ds < 2; ++ds) {
                bf16x8 vf = *(const bf16x8*)(Vh + (size_t)(ds * 16 + lr) * M_ + m0 + ks * 32 + lg * 8);
                acc[ds] = __builtin_amdgcn_mfma_f32_16x16x32_bf16(pf, vf, acc[ds], 0, 0, 0);
            }
        }
    }

    // epilogue: out[b, n0+n, h*32 + d] = acc / lsum   (f32)
#pragma unroll
    for (int ds = 0; ds < 2; ++ds) {
#pragma unroll
        for (int reg = 0; reg < 4; ++reg) {
            int n = lg * 4 + reg;
            out[((size_t)b * N_ + n0 + n) * C_ + h * DH_ + ds * 16 + lr] =
                acc[ds][reg] / lrun[reg];
        }
    }
}

// ---------------- launch ----------------------------------------------------
extern "C" void kernel_launch(void* const* d_in, const int* in_sizes, int n_in,
                              void* d_out, int out_size, void* d_ws, size_t ws_size,
                              hipStream_t stream) {
    const float* Xq = (const float*)d_in[0];
    const float* Xk = (const float*)d_in[1];
    const float* Xv = (const float*)d_in[2];
    const int* ridx = (const int*)d_in[3];
    const float* kmask = (const float*)d_in[4];
    const float* Wq = (const float*)d_in[5];
    const float* bq = (const float*)d_in[6];
    const float* Wk = (const float*)d_in[7];
    const float* bk = (const float*)d_in[8];
    const float* Wv = (const float*)d_in[9];
    const float* bv = (const float*)d_in[10];
    const float* rbank = (const float*)d_in[11];
    float* outp = (float*)d_out;

    char* ws = (char*)d_ws;
    __bf16* Wt = (__bf16*)ws;                               // 3*256*256*2 = 393216 B
    __bf16* qb = (__bf16*)(ws + 393216);                    // 4 MB
    __bf16* kb = (__bf16*)(ws + 393216 + 4194304);          // 4 MB
    __bf16* vt = (__bf16*)(ws + 393216 + 8388608);          // 4 MB

    wtrans_kernel<<<dim3(8, 8, 3), dim3(32, 8), 0, stream>>>(Wq, Wk, Wv, Wt);
    proj_kernel<<<dim3(128, 4, 3), 256, 0, stream>>>(Xq, Xk, Xv, bq, bk, bv, Wt, qb, kb, vt);
    attn_kernel<<<dim3(N_ / 16, B_), 512, 0, stream>>>(qb, kb, vt, ridx, kmask, rbank, outp);
}